// Round 1
// baseline (1135.187 us; speedup 1.0000x reference)
//
#include <hip/hip_runtime.h>

#define NTOK 49
#define NWIN 4096

typedef short  s8v  __attribute__((ext_vector_type(8)));
typedef float  v4f  __attribute__((ext_vector_type(4)));

__device__ __forceinline__ unsigned short f2b(float f){
  union { float f; unsigned u; } v; v.f = f;
  unsigned u = v.u;
  return (unsigned short)((u + 0x7fffu + ((u >> 16) & 1u)) >> 16);
}
__device__ __forceinline__ float b2f(unsigned short u){
  union { float f; unsigned u; } v; v.u = ((unsigned)u) << 16; return v.f;
}

// Repack a row-major f32 weight matrix [256][ncols] into bf16 MFMA B-fragment order.
// frag = ntile*8 + ks ; lane holds B[k = ks*32 + (lane>>4)*8 + j][n = ntile*16 + (lane&15)]
// stored at packed[(frag*64 + lane)*8 + j]  -> coalesced 16B/lane loads in the main kernel.
__global__ void repack_b(const float* __restrict__ w,
                         unsigned short* __restrict__ packed,
                         int ncols, int nfrag){
  int t = blockIdx.x * 256 + threadIdx.x;
  int frag = t >> 6;
  if (frag >= nfrag) return;
  int lane  = t & 63;
  int ntile = frag >> 3, ks = frag & 7;
  int n  = ntile * 16 + (lane & 15);
  int k0 = ks * 32 + (lane >> 4) * 8;
  unsigned short tmp[8];
#pragma unroll
  for (int j = 0; j < 8; ++j) tmp[j] = f2b(w[(size_t)(k0 + j) * ncols + n]);
  *(s8v*)(packed + (size_t)t * 8) = *(s8v*)tmp;
}

// LDS: 54256 B -> 3 blocks/CU (12 waves/CU), same occupancy as before but
// 9 barriers/block instead of 17 (kh/vt double-buffered; qh/p_s are wave-private rows).
__global__ __launch_bounds__(256, 3) void wattn_main(
    const float* __restrict__ xg,
    const float* __restrict__ bqkv,
    const float* __restrict__ bproj,
    const float* __restrict__ btab,
    const unsigned short* __restrict__ pwq,
    const unsigned short* __restrict__ pwp,
    float* __restrict__ outg)
{
  __shared__ __align__(16) unsigned short bias_s[169 * 8];     // bf16 bias * log2e
  __shared__ __align__(16) unsigned short aout_s[NTOK * 264];  // attention output, bf16
  __shared__ __align__(16) unsigned short qh_s[NTOK * 32];     // Q [token][hd] (wave-private rows)
  __shared__ __align__(16) unsigned short kh_s[2][NTOK * 32];  // K double-buffered by head parity
  __shared__ __align__(16) unsigned short vt_s[2][32 * 72];    // V^T double-buffered, pad tokens zeroed
  __shared__ __align__(16) unsigned short p_s[NTOK * 72];      // P rows (wave-private rows)

  const int tid  = threadIdx.x;
  const int wave = tid >> 6;
  const int lane = tid & 63;
  const int quad = lane >> 4;
  const int c16  = lane & 15;
  const int b    = blockIdx.x;
  const size_t xbase = (size_t)b * (NTOK * 256);

  const float LOG2E  = 1.4426950408889634f;
  const float QSCALE = 0.1767766952966369f * 1.4426950408889634f; // hd^-0.5 * log2e

  // ---- Phase 0: bias table (bf16, pre-multiplied by log2e) + zero vt pad tokens of BOTH buffers ----
  for (int i = tid; i < 169 * 8; i += 256) bias_s[i] = f2b(btab[i] * LOG2E);
  for (int i = tid; i < 2 * 32 * 15; i += 256){
    int bufn = i / (32 * 15), j = i % (32 * 15);
    int n = j / 15, t = NTOK + j % 15;
    vt_s[bufn][n * 72 + t] = 0;
  }

  // ---- x A-fragments from global f32 into registers (reused across all heads) ----
  int arow = wave * 16 + c16; if (arow > NTOK - 1) arow = NTOK - 1;  // clamp: dup rows discarded
  const float* xrow = xg + xbase + (size_t)arow * 256;
  s8v a_x[8];
#pragma unroll
  for (int ks = 0; ks < 8; ++ks){
    float4 v0 = *(const float4*)(xrow + ks * 32 + quad * 8);
    float4 v1 = *(const float4*)(xrow + ks * 32 + quad * 8 + 4);
    unsigned short t[8] = { f2b(v0.x), f2b(v0.y), f2b(v0.z), f2b(v0.w),
                            f2b(v1.x), f2b(v1.y), f2b(v1.z), f2b(v1.w) };
    a_x[ks] = *(s8v*)t;
  }

  const int rbase = wave * 16 + quad * 4;

  // ---- per-lane softmax-row constants (S^T layout: lane owns row srow = wave*16 + c16) ----
  int srow0 = wave * 16 + c16;
  const bool rowok = srow0 < NTOK;
  const int srow  = rowok ? srow0 : (NTOK - 1);
  int boff[4][4];   // rel-bias element offsets (x8 for head stride), precomputed once
  {
    int rh = srow / 7, rw = srow - rh * 7;
#pragma unroll
    for (int nt = 0; nt < 4; ++nt)
#pragma unroll
      for (int r = 0; r < 4; ++r){
        int col = nt * 16 + quad * 4 + r;
        if (col > NTOK - 1) col = NTOK - 1;
        int ch = col / 7, cw = col - ch * 7;
        boff[nt][r] = ((rh - ch + 6) * 13 + (rw - cw + 6)) << 3;
      }
  }

  // ---- prefetch head 0, ks=0 weight fragments ----
  s8v bpre[6];
#pragma unroll
  for (int nt = 0; nt < 6; ++nt){
    int ntg = (nt >> 1) * 16 + (nt & 1);  // h = 0
    bpre[nt] = *(const s8v*)(pwq + ((size_t)(ntg * 8) * 64 + lane) * 8);
  }

  // ================= head loop (ONE barrier per head) =================
  for (int h = 0; h < 8; ++h){
    unsigned short* kcur = kh_s[h & 1];
    unsigned short* vcur = vt_s[h & 1];

    // ---- per-head qkv GEMM: own 16-row m-tile x 6 n-tiles (q0 q1 k0 k1 v0 v1) ----
    v4f acc[6];
#pragma unroll
    for (int nt = 0; nt < 6; ++nt) acc[nt] = (v4f){0.f, 0.f, 0.f, 0.f};
    // ks = 0 from prefetched fragments (loaded during previous head's S/PV phase)
#pragma unroll
    for (int nt = 0; nt < 6; ++nt)
      acc[nt] = __builtin_amdgcn_mfma_f32_16x16x32_bf16(a_x[0], bpre[nt], acc[nt], 0, 0, 0);
#pragma unroll
    for (int ks = 1; ks < 8; ++ks){
#pragma unroll
      for (int nt = 0; nt < 6; ++nt){
        int ntg = (nt >> 1) * 16 + 2 * h + (nt & 1);
        s8v bb = *(const s8v*)(pwq + ((size_t)(ntg * 8 + ks) * 64 + lane) * 8);
        acc[nt] = __builtin_amdgcn_mfma_f32_16x16x32_bf16(a_x[ks], bb, acc[nt], 0, 0, 0);
      }
    }

    // ---- epilogue: Q (scaled by hd^-0.5*log2e) and K row-major [token][32]; V transposed ----
#pragma unroll
    for (int nt = 0; nt < 4; ++nt){
      int sec  = nt >> 1;                       // 0 = q, 1 = k
      int wcol = (nt & 1) * 16 + c16;
      float bq = bqkv[sec * 256 + h * 32 + wcol];
      unsigned short* dst = sec ? kcur : qh_s;
#pragma unroll
      for (int reg = 0; reg < 4; ++reg){
        int row = rbase + reg;
        float v = acc[nt][reg] + bq;
        if (sec == 0) v *= QSCALE;
        if (row < NTOK) dst[row * 32 + wcol] = f2b(v);
      }
    }
#pragma unroll
    for (int nt = 4; nt < 6; ++nt){
      int vcol = (nt - 4) * 16 + c16;
      float bq = bqkv[512 + h * 32 + vcol];
      unsigned short t[4];
#pragma unroll
      for (int reg = 0; reg < 4; ++reg) t[reg] = f2b(acc[nt][reg] + bq);
      if (rbase + 3 < NTOK)
        *(unsigned long long*)(vcur + vcol * 72 + rbase) = *(unsigned long long*)t;
      else {
#pragma unroll
        for (int reg = 0; reg < 4; ++reg)
          if (rbase + reg < NTOK) vcur[vcol * 72 + rbase + reg] = t[reg];
      }
    }
    __syncthreads();   // kh/vt of head h visible; double-buffering protects head h-1 readers

    // ---- prefetch next head ks=0 fragments; latency hides under S/softmax/PV ----
    if (h < 7){
#pragma unroll
      for (int nt = 0; nt < 6; ++nt){
        int ntg = (nt >> 1) * 16 + 2 * (h + 1) + (nt & 1);
        bpre[nt] = *(const s8v*)(pwq + ((size_t)(ntg * 8) * 64 + lane) * 8);
      }
    }

    // ---- S^T = K (Q*scale)^T + bias: lane owns full softmax row srow ----
    s8v aq = *(const s8v*)(qh_s + srow * 32 + quad * 8);
    v4f s[4];
#pragma unroll
    for (int nt = 0; nt < 4; ++nt){
      int tok = nt * 16 + c16; if (tok > NTOK - 1) tok = NTOK - 1;
      s8v bk = *(const s8v*)(kcur + tok * 32 + quad * 8);
      v4f z = (v4f){0.f, 0.f, 0.f, 0.f};
      s[nt] = __builtin_amdgcn_mfma_f32_16x16x32_bf16(bk, aq, z, 0, 0, 0);  // S[srow][16nt+4q+r]
    }

    // ---- softmax: in-register row reduce + 2 shuffles (vs 32 before) ----
    float m = -1e38f;
#pragma unroll
    for (int nt = 0; nt < 4; ++nt)
#pragma unroll
      for (int r = 0; r < 4; ++r){
        if (nt < 3){
          s[nt][r] += b2f(bias_s[boff[nt][r] + h]);       // cols 0..47 always valid
        } else if (r == 0){
          float wb = s[3][0] + b2f(bias_s[boff[3][0] + h]);
          s[3][0] = (quad == 0) ? wb : -1e38f;            // col 48 valid only for quad 0
        } else {
          s[nt][r] = -1e38f;                              // cols 49..63 masked
        }
        m = fmaxf(m, s[nt][r]);
      }
    m = fmaxf(m, __shfl_xor(m, 16, 64));
    m = fmaxf(m, __shfl_xor(m, 32, 64));
    float p[4][4], sum = 0.f;
#pragma unroll
    for (int nt = 0; nt < 4; ++nt)
#pragma unroll
      for (int r = 0; r < 4; ++r){
        p[nt][r] = exp2f(s[nt][r] - m);                   // log2e folded into Q and bias
        sum += p[nt][r];
      }
    sum += __shfl_xor(sum, 16, 64);
    sum += __shfl_xor(sum, 32, 64);
    float inv = 1.0f / sum;

    if (rowok){
#pragma unroll
      for (int nt = 0; nt < 4; ++nt){
        unsigned short t[4] = { f2b(p[nt][0] * inv), f2b(p[nt][1] * inv),
                                f2b(p[nt][2] * inv), f2b(p[nt][3] * inv) };
        *(unsigned long long*)(p_s + srow * 72 + nt * 16 + quad * 4) = *(unsigned long long*)t;
      }
    }

    // ---- PV (wave-private P rows; no barrier needed between p_s write and read) ----
    v4f o[2];
    o[0] = (v4f){0.f, 0.f, 0.f, 0.f};
    o[1] = (v4f){0.f, 0.f, 0.f, 0.f};
#pragma unroll
    for (int ks = 0; ks < 2; ++ks){
      s8v ap = *(const s8v*)(p_s + srow * 72 + ks * 32 + quad * 8);
#pragma unroll
      for (int nt = 0; nt < 2; ++nt){
        s8v bv = *(const s8v*)(vcur + (nt * 16 + c16) * 72 + ks * 32 + quad * 8);
        o[nt] = __builtin_amdgcn_mfma_f32_16x16x32_bf16(ap, bv, o[nt], 0, 0, 0);
      }
    }
#pragma unroll
    for (int nt = 0; nt < 2; ++nt)
#pragma unroll
      for (int reg = 0; reg < 4; ++reg){
        int row = rbase + reg;
        if (row < NTOK) aout_s[row * 264 + h * 32 + nt * 16 + c16] = f2b(o[nt][reg]);
      }
  } // heads
  __syncthreads();   // aout complete across waves

  // ---- Phase 4: out = aout @ Wproj + b_proj (wave covers n-tiles wave*4..wave*4+3) ----
  {
    v4f acc[4][4];
#pragma unroll
    for (int mti = 0; mti < 4; ++mti)
#pragma unroll
      for (int nt = 0; nt < 4; ++nt) acc[mti][nt] = (v4f){0.f, 0.f, 0.f, 0.f};
#pragma unroll
    for (int ks = 0; ks < 8; ++ks){
      s8v a[4], bw[4];
#pragma unroll
      for (int mti = 0; mti < 4; ++mti){
        int r = mti * 16 + c16; if (r > NTOK - 1) r = NTOK - 1;
        a[mti] = *(const s8v*)(aout_s + r * 264 + ks * 32 + quad * 8);
      }
#pragma unroll
      for (int nt = 0; nt < 4; ++nt){
        int ntg = wave * 4 + nt;
        bw[nt] = *(const s8v*)(pwp + ((size_t)(ntg * 8 + ks) * 64 + lane) * 8);
      }
#pragma unroll
      for (int mti = 0; mti < 4; ++mti)
#pragma unroll
        for (int nt = 0; nt < 4; ++nt)
          acc[mti][nt] = __builtin_amdgcn_mfma_f32_16x16x32_bf16(a[mti], bw[nt], acc[mti][nt], 0, 0, 0);
    }
#pragma unroll
    for (int nt = 0; nt < 4; ++nt){
      int col = wave * 64 + nt * 16 + c16;
      float bp = bproj[col];
#pragma unroll
      for (int mti = 0; mti < 4; ++mti)
#pragma unroll
        for (int reg = 0; reg < 4; ++reg){
          int row = mti * 16 + quad * 4 + reg;
          if (row < NTOK)
            outg[xbase + (size_t)row * 256 + col] = acc[mti][nt][reg] + bp;
        }
    }
  }
}

extern "C" void kernel_launch(void* const* d_in, const int* in_sizes, int n_in,
                              void* d_out, int out_size, void* d_ws, size_t ws_size,
                              hipStream_t stream){
  const float* x     = (const float*)d_in[0];
  const float* wqkv  = (const float*)d_in[1];
  const float* bqkv  = (const float*)d_in[2];
  const float* wproj = (const float*)d_in[3];
  const float* bproj = (const float*)d_in[4];
  const float* btab  = (const float*)d_in[5];
  float* out = (float*)d_out;

  unsigned short* pwq = (unsigned short*)d_ws;          // 48*8*64*8 = 196608 elems (384 KB)
  unsigned short* pwp = pwq + 196608;                   // 16*8*64*8 =  65536 elems (128 KB)

  repack_b<<<96, 256, 0, stream>>>(wqkv, pwq, 768, 384);
  repack_b<<<32, 256, 0, stream>>>(wproj, pwp, 256, 128);

  wattn_main<<<NWIN, 256, 0, stream>>>(x, bqkv, bproj, btab, pwq, pwp, out);
}

// Round 2
// 839.076 us; speedup vs baseline: 1.3529x; 1.3529x over previous
//
#include <hip/hip_runtime.h>

#define NTOK 49
#define NWIN 4096

typedef short  s8v  __attribute__((ext_vector_type(8)));
typedef float  v4f  __attribute__((ext_vector_type(4)));

__device__ __forceinline__ unsigned short f2b(float f){
  union { float f; unsigned u; } v; v.f = f;
  unsigned u = v.u;
  return (unsigned short)((u + 0x7fffu + ((u >> 16) & 1u)) >> 16);
}
__device__ __forceinline__ float b2f(unsigned short u){
  union { float f; unsigned u; } v; v.u = ((unsigned)u) << 16; return v.f;
}

// Repack a row-major f32 weight matrix [256][ncols] into bf16 MFMA B-fragment order.
// frag = ntile*8 + ks ; lane holds B[k = ks*32 + (lane>>4)*8 + j][n = ntile*16 + (lane&15)]
// stored at packed[(frag*64 + lane)*8 + j]  -> coalesced 16B/lane loads in the main kernel.
__global__ void repack_b(const float* __restrict__ w,
                         unsigned short* __restrict__ packed,
                         int ncols, int nfrag){
  int t = blockIdx.x * 256 + threadIdx.x;
  int frag = t >> 6;
  if (frag >= nfrag) return;
  int lane  = t & 63;
  int ntile = frag >> 3, ks = frag & 7;
  int n  = ntile * 16 + (lane & 15);
  int k0 = ks * 32 + (lane >> 4) * 8;
  unsigned short tmp[8];
#pragma unroll
  for (int j = 0; j < 8; ++j) tmp[j] = f2b(w[(size_t)(k0 + j) * ncols + n]);
  *(s8v*)(packed + (size_t)t * 8) = *(s8v*)tmp;
}

// LDS: 48080 B -> 3 blocks/CU (12 waves/CU). Single-buffered kh/vt (2 barriers/head);
// QKV GEMM of head h+1 is scheduled INSIDE the S/softmax/PV region of head h so the
// 48 L2 weight loads overlap the attention latency chain.
__global__ __launch_bounds__(256, 3) void wattn_main(
    const float* __restrict__ xg,
    const float* __restrict__ bqkv,
    const float* __restrict__ bproj,
    const float* __restrict__ btab,
    const unsigned short* __restrict__ pwq,
    const unsigned short* __restrict__ pwp,
    float* __restrict__ outg)
{
  __shared__ __align__(16) unsigned short bias_s[169 * 8];     // bf16 bias * log2e
  __shared__ __align__(16) unsigned short aout_s[NTOK * 264];  // attention output, bf16
  __shared__ __align__(16) unsigned short qh_s[NTOK * 40];     // Q [token][hd], stride 40 (bank-friendly)
  __shared__ __align__(16) unsigned short kh_s[NTOK * 40];     // K [token][hd], stride 40
  __shared__ __align__(16) unsigned short vt_s[32 * 72];       // V^T [hd][token], pad tokens zeroed
  __shared__ __align__(16) unsigned short p_s[NTOK * 72];      // P rows (wave-private)

  const int tid  = threadIdx.x;
  const int wave = tid >> 6;
  const int lane = tid & 63;
  const int quad = lane >> 4;
  const int c16  = lane & 15;
  const int b    = blockIdx.x;
  const size_t xbase = (size_t)b * (NTOK * 256);

  const float LOG2E  = 1.4426950408889634f;
  const float QSCALE = 0.1767766952966369f * 1.4426950408889634f; // hd^-0.5 * log2e

  // ---- Phase 0: bias table (bf16, pre-multiplied by log2e) + zero vt pad tokens once ----
  for (int i = tid; i < 169 * 8; i += 256) bias_s[i] = f2b(btab[i] * LOG2E);
  for (int i = tid; i < 32 * 15; i += 256){
    int n = i / 15, t = NTOK + i % 15;
    vt_s[n * 72 + t] = 0;
  }

  // ---- x A-fragments from global f32 into registers (reused across all heads) ----
  int arow = wave * 16 + c16; if (arow > NTOK - 1) arow = NTOK - 1;  // clamp: dup rows discarded
  const float* xrow = xg + xbase + (size_t)arow * 256;
  s8v a_x[8];
#pragma unroll
  for (int ks = 0; ks < 8; ++ks){
    float4 v0 = *(const float4*)(xrow + ks * 32 + quad * 8);
    float4 v1 = *(const float4*)(xrow + ks * 32 + quad * 8 + 4);
    unsigned short t[8] = { f2b(v0.x), f2b(v0.y), f2b(v0.z), f2b(v0.w),
                            f2b(v1.x), f2b(v1.y), f2b(v1.z), f2b(v1.w) };
    a_x[ks] = *(s8v*)t;
  }

  const int rbase = wave * 16 + quad * 4;

  // ---- per-lane softmax-row constants (S^T layout: lane owns row srow = wave*16 + c16) ----
  int srow0 = wave * 16 + c16;
  const bool rowok = srow0 < NTOK;
  const int srow  = rowok ? srow0 : (NTOK - 1);
  int boff[4][4];   // rel-bias element offsets (x8 for head stride), precomputed once
  {
    int rh = srow / 7, rw = srow - rh * 7;
#pragma unroll
    for (int nt = 0; nt < 4; ++nt)
#pragma unroll
      for (int r = 0; r < 4; ++r){
        int col = nt * 16 + quad * 4 + r;
        if (col > NTOK - 1) col = NTOK - 1;
        int ch = col / 7, cw = col - ch * 7;
        boff[nt][r] = ((rh - ch + 6) * 13 + (rw - cw + 6)) << 3;
      }
  }

  // ---- QKV GEMM for one head: 16-row m-tile x 6 n-tiles (q0 q1 k0 k1 v0 v1) ----
  auto qkv_gemm = [&](int hh, v4f* acc){
#pragma unroll
    for (int nt = 0; nt < 6; ++nt) acc[nt] = (v4f){0.f, 0.f, 0.f, 0.f};
#pragma unroll
    for (int ks = 0; ks < 8; ++ks)
#pragma unroll
      for (int nt = 0; nt < 6; ++nt){
        int ntg = (nt >> 1) * 16 + 2 * hh + (nt & 1);
        s8v bb = *(const s8v*)(pwq + ((size_t)(ntg * 8 + ks) * 64 + lane) * 8);
        acc[nt] = __builtin_amdgcn_mfma_f32_16x16x32_bf16(a_x[ks], bb, acc[nt], 0, 0, 0);
      }
  };

  // ---- epilogue: Q (pre-scaled) and K row-major [token][40]; V transposed [hd][72] ----
  auto epilogue = [&](int hh, v4f* acc){
#pragma unroll
    for (int nt = 0; nt < 4; ++nt){
      int sec  = nt >> 1;                       // 0 = q, 1 = k
      int wcol = (nt & 1) * 16 + c16;
      float bq = bqkv[sec * 256 + hh * 32 + wcol];
      unsigned short* dst = sec ? kh_s : qh_s;
#pragma unroll
      for (int reg = 0; reg < 4; ++reg){
        int row = rbase + reg;
        float v = acc[nt][reg] + bq;
        if (sec == 0) v *= QSCALE;
        if (row < NTOK) dst[row * 40 + wcol] = f2b(v);
      }
    }
#pragma unroll
    for (int nt = 4; nt < 6; ++nt){
      int vcol = (nt - 4) * 16 + c16;
      float bq = bqkv[512 + hh * 32 + vcol];
      unsigned short t[4];
#pragma unroll
      for (int reg = 0; reg < 4; ++reg) t[reg] = f2b(acc[nt][reg] + bq);
      if (rbase + 3 < NTOK)
        *(unsigned long long*)(vt_s + vcol * 72 + rbase) = *(unsigned long long*)t;
      else {
#pragma unroll
        for (int reg = 0; reg < 4; ++reg)
          if (rbase + reg < NTOK) vt_s[vcol * 72 + rbase + reg] = t[reg];
      }
    }
  };

  // ---- prologue: head 0 qkv + epilogue, then one barrier (also covers phase 0) ----
  v4f accn[6];
  qkv_gemm(0, accn);
  epilogue(0, accn);
  __syncthreads();

  // ================= head loop =================
  for (int h = 0; h < 8; ++h){
    // S-phase LDS reads issued first: their latency hides under the QKV(h+1) load pipeline
    s8v aq = *(const s8v*)(qh_s + srow * 40 + quad * 8);
    s8v bk[4];
#pragma unroll
    for (int nt = 0; nt < 4; ++nt){
      int tok = nt * 16 + c16; if (tok > NTOK - 1) tok = NTOK - 1;
      bk[nt] = *(const s8v*)(kh_s + tok * 40 + quad * 8);
    }

    // QKV GEMM for head h+1 — register-only, same scheduling region as S/softmax/PV(h)
    if (h < 7) qkv_gemm(h + 1, accn);

    // ---- S^T = K (Q*scale)^T: lane owns full softmax row srow ----
    v4f s[4];
#pragma unroll
    for (int nt = 0; nt < 4; ++nt){
      v4f z = (v4f){0.f, 0.f, 0.f, 0.f};
      s[nt] = __builtin_amdgcn_mfma_f32_16x16x32_bf16(bk[nt], aq, z, 0, 0, 0); // S[srow][16nt+4q+r]
    }

    // ---- softmax: in-register row reduce + 2 shuffles ----
    float m = -1e38f;
#pragma unroll
    for (int nt = 0; nt < 4; ++nt)
#pragma unroll
      for (int r = 0; r < 4; ++r){
        if (nt < 3){
          s[nt][r] += b2f(bias_s[boff[nt][r] + h]);       // cols 0..47 always valid
        } else if (r == 0){
          float wb = s[3][0] + b2f(bias_s[boff[3][0] + h]);
          s[3][0] = (quad == 0) ? wb : -1e38f;            // col 48 valid only for quad 0
        } else {
          s[nt][r] = -1e38f;                              // cols 49..63 masked
        }
        m = fmaxf(m, s[nt][r]);
      }
    m = fmaxf(m, __shfl_xor(m, 16, 64));
    m = fmaxf(m, __shfl_xor(m, 32, 64));
    float p[4][4], sum = 0.f;
#pragma unroll
    for (int nt = 0; nt < 4; ++nt)
#pragma unroll
      for (int r = 0; r < 4; ++r){
        p[nt][r] = exp2f(s[nt][r] - m);                   // log2e folded into Q and bias
        sum += p[nt][r];
      }
    sum += __shfl_xor(sum, 16, 64);
    sum += __shfl_xor(sum, 32, 64);
    float inv = 1.0f / sum;

    if (rowok){
#pragma unroll
      for (int nt = 0; nt < 4; ++nt){
        unsigned short t[4] = { f2b(p[nt][0] * inv), f2b(p[nt][1] * inv),
                                f2b(p[nt][2] * inv), f2b(p[nt][3] * inv) };
        *(unsigned long long*)(p_s + srow * 72 + nt * 16 + quad * 4) = *(unsigned long long*)t;
      }
    }

    // ---- PV (wave-private P rows; same-wave DS ordering, no barrier needed) ----
    v4f o[2];
    o[0] = (v4f){0.f, 0.f, 0.f, 0.f};
    o[1] = (v4f){0.f, 0.f, 0.f, 0.f};
#pragma unroll
    for (int ks = 0; ks < 2; ++ks){
      s8v ap = *(const s8v*)(p_s + srow * 72 + ks * 32 + quad * 8);
#pragma unroll
      for (int nt = 0; nt < 2; ++nt){
        s8v bv = *(const s8v*)(vt_s + (nt * 16 + c16) * 72 + ks * 32 + quad * 8);
        o[nt] = __builtin_amdgcn_mfma_f32_16x16x32_bf16(ap, bv, o[nt], 0, 0, 0);
      }
    }
#pragma unroll
    for (int nt = 0; nt < 2; ++nt)
#pragma unroll
      for (int reg = 0; reg < 4; ++reg){
        int row = rbase + reg;
        if (row < NTOK) aout_s[row * 264 + h * 32 + nt * 16 + c16] = f2b(o[nt][reg]);
      }

    __syncthreads();                 // all reads of qh/kh/vt (head h) complete
    if (h < 7){
      epilogue(h + 1, accn);         // write next head's qh/kh/vt
      __syncthreads();               // visible for next iteration's S-phase
    }
  } // heads
  // aout_s writes of head 7 were made visible by the last barrier above

  // ---- Phase 4: out = aout @ Wproj + b_proj (wave covers n-tiles wave*4..wave*4+3) ----
  {
    v4f acc[4][4];
#pragma unroll
    for (int mti = 0; mti < 4; ++mti)
#pragma unroll
      for (int nt = 0; nt < 4; ++nt) acc[mti][nt] = (v4f){0.f, 0.f, 0.f, 0.f};
#pragma unroll
    for (int ks = 0; ks < 8; ++ks){
      s8v a[4], bw[4];
#pragma unroll
      for (int mti = 0; mti < 4; ++mti){
        int r = mti * 16 + c16; if (r > NTOK - 1) r = NTOK - 1;
        a[mti] = *(const s8v*)(aout_s + r * 264 + ks * 32 + quad * 8);
      }
#pragma unroll
      for (int nt = 0; nt < 4; ++nt){
        int ntg = wave * 4 + nt;
        bw[nt] = *(const s8v*)(pwp + ((size_t)(ntg * 8 + ks) * 64 + lane) * 8);
      }
#pragma unroll
      for (int mti = 0; mti < 4; ++mti)
#pragma unroll
        for (int nt = 0; nt < 4; ++nt)
          acc[mti][nt] = __builtin_amdgcn_mfma_f32_16x16x32_bf16(a[mti], bw[nt], acc[mti][nt], 0, 0, 0);
    }
#pragma unroll
    for (int nt = 0; nt < 4; ++nt){
      int col = wave * 64 + nt * 16 + c16;
      float bp = bproj[col];
#pragma unroll
      for (int mti = 0; mti < 4; ++mti)
#pragma unroll
        for (int reg = 0; reg < 4; ++reg){
          int row = mti * 16 + quad * 4 + reg;
          if (row < NTOK)
            outg[xbase + (size_t)row * 256 + col] = acc[mti][nt][reg] + bp;
        }
    }
  }
}

extern "C" void kernel_launch(void* const* d_in, const int* in_sizes, int n_in,
                              void* d_out, int out_size, void* d_ws, size_t ws_size,
                              hipStream_t stream){
  const float* x     = (const float*)d_in[0];
  const float* wqkv  = (const float*)d_in[1];
  const float* bqkv  = (const float*)d_in[2];
  const float* wproj = (const float*)d_in[3];
  const float* bproj = (const float*)d_in[4];
  const float* btab  = (const float*)d_in[5];
  float* out = (float*)d_out;

  unsigned short* pwq = (unsigned short*)d_ws;          // 48*8*64*8 = 196608 elems (384 KB)
  unsigned short* pwp = pwq + 196608;                   // 16*8*64*8 =  65536 elems (128 KB)

  repack_b<<<96, 256, 0, stream>>>(wqkv, pwq, 768, 384);
  repack_b<<<32, 256, 0, stream>>>(wproj, pwp, 256, 128);

  wattn_main<<<NWIN, 256, 0, stream>>>(x, bqkv, bproj, btab, pwq, pwp, out);
}